// Round 5
// baseline (394.643 us; speedup 1.0000x reference)
//
#include <hip/hip_runtime.h>
#include <stdint.h>

typedef short short8_t __attribute__((ext_vector_type(8)));
typedef float f32x4    __attribute__((ext_vector_type(4)));
typedef float f32x16   __attribute__((ext_vector_type(16)));

__device__ __forceinline__ unsigned short f2bf(float f) {
  unsigned int u = __float_as_uint(f);
  u += 0x7FFFu + ((u >> 16) & 1u);          // round-to-nearest-even
  return (unsigned short)(u >> 16);
}

// async global->LDS, 16B per lane; LDS dest = wave-uniform base + lane*16
__device__ __forceinline__ void glld16(const void* src, char* lds) {
  __builtin_amdgcn_global_load_lds(
      (const __attribute__((address_space(1))) void*)src,
      (__attribute__((address_space(3))) void*)lds, 16, 0, 0);
}

// swizzled b128 LDS read: XOR bits 4-6 keyed on bits 7-9 (matches pre-swizzled source)
__device__ __forceinline__ short8_t lds_rd(const char* smem, int a) {
  int aa = a ^ (((a >> 7) & 7) << 4);
  return *(const short8_t*)(smem + aa);
}

// ---------- kernel 1: min/max of conv_weight ----------
__global__ __launch_bounds__(256) void minmax_kernel(const float* __restrict__ w,
                                                     float* __restrict__ mm) {
  int tid = threadIdx.x;
  float mn = 1e30f, mx = -1e30f;
  const float4* w4 = (const float4*)w;      // 9216 float4
  for (int i = tid; i < 9216; i += 256) {
    float4 v = w4[i];
    mn = fminf(mn, fminf(fminf(v.x, v.y), fminf(v.z, v.w)));
    mx = fmaxf(mx, fmaxf(fmaxf(v.x, v.y), fmaxf(v.z, v.w)));
  }
  for (int off = 32; off; off >>= 1) {
    mn = fminf(mn, __shfl_down(mn, off));
    mx = fmaxf(mx, __shfl_down(mx, off));
  }
  __shared__ float smn[4], smx[4];
  if ((tid & 63) == 0) { smn[tid >> 6] = mn; smx[tid >> 6] = mx; }
  __syncthreads();
  if (tid == 0) {
    mn = fminf(fminf(smn[0], smn[1]), fminf(smn[2], smn[3]));
    mx = fmaxf(fmaxf(smx[0], smx[1]), fmaxf(smx[2], smx[3]));
    mm[0] = mn; mm[1] = mx;
  }
}

// ---------- kernel 2: hash weights -> bf16, 32x32x16 A-fragment layout ----------
// frag f = mt*4 + ks;  lane = (k>>3)*32 + (co&31);  elem = k&7;  k = ci&15; ks = ci>>4.
// dst = ((tap*8 + f)*64 + lane)*8 + elem   -> conv reads one coalesced dwordx4 per frag.
__global__ __launch_bounds__(256) void hashprep_kernel(const float* __restrict__ w,
                                                       const float* __restrict__ hv,
                                                       const float* __restrict__ mm,
                                                       unsigned short* __restrict__ w0,
                                                       unsigned short* __restrict__ w1) {
  int t = blockIdx.x * 256 + threadIdx.x;   // 0..36863, layout [co][ci][kh][kw]
  if (t >= 36864) return;
  float mn = mm[0], mx = mm[1];
  float width = (mx - mn) / 256.0f;
  float wv = w[t];
  int idx = min(max((int)floorf((wv - mn) / width), 0), 255);
  float hw = hv[idx];
  int co  = t / 576;
  int rem = t - co * 576;
  int ci  = rem / 9;
  int tap = rem - ci * 9;
  int mt = co >> 5, m = co & 31;
  int ks = ci >> 4, k = ci & 15;
  int f = mt * 4 + ks;
  int lane = (k >> 3) * 32 + m;
  int dst = ((tap * 8 + f) * 64 + lane) * 8 + (k & 7);
  w0[dst] = f2bf(wv);
  w1[dst] = f2bf(hw);
}

// ---------- kernel 3 (fused x & x_hash): f32 NCHW -> bf16 [b][h][w' 0..129][ci] ----------
// LDS [128][64] ushort (16KB), c-index XOR swizzle c' = c ^ ((w>>2 &7)<<3)  (bijective per
// row, preserves 8-blocks & pair order). Writes: packed 2-ch ds_write_b32 (4-way conflict);
// reads: ds_read_b128 conflict-free; global reads float4-coalesced, stores short8-coalesced.
__global__ __launch_bounds__(256) void xprep_kernel(const float* __restrict__ x,
                                                    const float* __restrict__ xh,
                                                    unsigned short* __restrict__ xbf,
                                                    unsigned short* __restrict__ xhbf) {
  __shared__ unsigned short T[128 * 64];
  int t   = threadIdx.x;
  int bid = blockIdx.x;
  int which = bid >> 11;
  int bh = bid & 2047;                       // b*128 + h
  const float* src = which ? xh : x;
  unsigned short* dst = which ? xhbf : xbf;
  int b = bh >> 7, h = bh & 127;
  const f32x4* x4 = (const f32x4*)src;
  size_t xrow = (((size_t)(b * 64) * 128 + h) << 5);   // float4 idx at c=0
  #pragma unroll
  for (int kk = 0; kk < 4; ++kk) {
    int j = kk * 256 + t;                    // < 1024
    int c2 = j >> 5, w4 = j & 31;
    int c = c2 * 2;
    f32x4 v0 = x4[xrow + ((size_t)c << 12) + w4];
    f32x4 v1 = x4[xrow + ((size_t)(c + 1) << 12) + w4];
    int cs = c ^ ((w4 & 7) << 3);            // (w>>2)&7 == w4&7
    #pragma unroll
    for (int jj = 0; jj < 4; ++jj) {
      int w = w4 * 4 + jj;
      unsigned int pk = (unsigned int)f2bf(v0[jj]) | ((unsigned int)f2bf(v1[jj]) << 16);
      *(unsigned int*)&T[w * 64 + cs] = pk;
    }
  }
  __syncthreads();
  size_t rb = (size_t)bh * (130 * 64);       // ushort index of output row base
  if (t < 16) {                              // zero halo columns w'=0 and w'=129
    short8_t z = {0, 0, 0, 0, 0, 0, 0, 0};
    int col = (t < 8) ? 0 : 129, ch = t & 7;
    *(short8_t*)(dst + rb + col * 64 + ch * 8) = z;
  }
  #pragma unroll
  for (int kk = 0; kk < 4; ++kk) {
    int q = kk * 256 + t;                    // < 1024
    int w = q >> 3, c0 = (q & 7) * 8;
    int cs0 = c0 ^ (((w >> 2) & 7) << 3);
    short8_t v = *(const short8_t*)&T[w * 64 + cs0];
    *(short8_t*)(dst + rb + (size_t)(w + 1) * 64 + c0) = v;
  }
}

// ---------- kernel 4: all three convs fused, 32x32x16 MFMA, W in registers ----------
// grid 2048: which = swz_bx>>10. 4 waves, 2 blocks/CU (LDS 50688B, ~225 VGPR).
// Block = 64co x 4h x 64w; wave = 1 h-row. X via global_load_lds; ONE barrier total.
#define XR 8448   // staged row: 66 cols * 128B

__global__ __launch_bounds__(256, 2) void conv_kernel(
    const unsigned short* __restrict__ xbf,
    const unsigned short* __restrict__ xhbf,
    const char* __restrict__ zeropage,      // >= 8560 zeroed bytes
    const unsigned short* __restrict__ wf0,
    const unsigned short* __restrict__ wf1,
    const float* __restrict__ bias,
    float* __restrict__ out0,               // out
    float* __restrict__ out1,               // hash_out
    float* __restrict__ out2) {             // out_hash

  __shared__ char smem[6 * XR];

  int tid = threadIdx.x, lane = tid & 63, wv = tid >> 6;
  int nlo = lane & 31, hi = lane >> 5;

  int bx0 = blockIdx.x;
  int bx  = (bx0 & 7) * 256 + (bx0 >> 3);   // bijective XCD swizzle (2048 % 8 == 0)
  int which = bx >> 10;
  int r10 = bx & 1023;
  int b = r10 >> 6, rowblk = (r10 >> 1) & 31, wblk = r10 & 1;
  int h0 = rowblk * 4, W0 = wblk * 64;
  int nsets = 2 - which;

  const unsigned short* xsrc  = which ? xhbf : xbf;
  const unsigned short* wsrc0 = which ? wf1 : wf0;
  float* o0 = which ? out2 : out0;

  // preload W tap 0 (overlaps X staging)
  short8_t aw0[8], aw1[8];
  #pragma unroll
  for (int i = 0; i < 8; ++i)
    aw0[i] = *(const short8_t*)(wsrc0 + i * 512 + lane * 8);
  if (nsets == 2) {
    #pragma unroll
    for (int i = 0; i < 8; ++i)
      aw1[i] = *(const short8_t*)(wf1 + i * 512 + lane * 8);
  }

  // stage X: 6 rows (h0-1 .. h0+4) x 66 cols x 64c = 3168 16B chunks
  const char* xb = (const char*)xsrc + (size_t)b * (130 * 128 * 128) + (size_t)W0 * 128;
  for (int batch = wv; batch < 50; batch += 4) {
    int q = batch * 64 + lane;
    if (q < 3168) {
      int r = q / 528;
      int o = (q - r * 528) << 4;
      int swz = o ^ (((q >> 3) & 7) << 4);
      int hin = h0 + r - 1;
      const char* src = ((unsigned)hin < 128u) ? (xb + (size_t)hin * 16640 + swz)
                                               : (zeropage + swz);
      glld16(src, smem + batch * 1024);
    }
  }

  f32x16 acc0[2][2], acc1[2][2];
  #pragma unroll
  for (int i = 0; i < 2; ++i)
    #pragma unroll
    for (int j = 0; j < 2; ++j) {
      #pragma unroll
      for (int e = 0; e < 16; ++e) { acc0[i][j][e] = 0.f; acc1[i][j][e] = 0.f; }
    }

  __syncthreads();                          // X (and W tap0) resident

  #pragma unroll
  for (int t = 0; t < 9; ++t) {
    if (t) {
      #pragma unroll
      for (int i = 0; i < 8; ++i)
        aw0[i] = *(const short8_t*)(wsrc0 + t * 4096 + i * 512 + lane * 8);
      if (nsets == 2) {
        #pragma unroll
        for (int i = 0; i < 8; ++i)
          aw1[i] = *(const short8_t*)(wf1 + t * 4096 + i * 512 + lane * 8);
      }
    }
    int kh = t / 3, kw = t - kh * 3;
    int xbase = (wv + kh) * XR + (kw << 7) + (hi << 4);
    #pragma unroll
    for (int ks = 0; ks < 4; ++ks) {
      short8_t bf[2];
      #pragma unroll
      for (int nf = 0; nf < 2; ++nf)
        bf[nf] = lds_rd(smem, xbase + ((nf * 32 + nlo) << 7) + (ks << 5));
      #pragma unroll
      for (int mt = 0; mt < 2; ++mt)
        #pragma unroll
        for (int nf = 0; nf < 2; ++nf)
          acc0[mt][nf] = __builtin_amdgcn_mfma_f32_32x32x16_bf16(
              aw0[mt * 4 + ks], bf[nf], acc0[mt][nf], 0, 0, 0);
      if (nsets == 2) {
        #pragma unroll
        for (int mt = 0; mt < 2; ++mt)
          #pragma unroll
          for (int nf = 0; nf < 2; ++nf)
            acc1[mt][nf] = __builtin_amdgcn_mfma_f32_32x32x16_bf16(
                aw1[mt * 4 + ks], bf[nf], acc1[mt][nf], 0, 0, 0);
      }
    }
  }

  // epilogue: C/D col = lane&31, row = (r&3) + 8*(r>>2) + 4*(lane>>5)  [m74/m101]
  size_t ob = (size_t)b * 64 * 16384 + (size_t)(h0 + wv) * 128 + W0;
  #pragma unroll
  for (int mt = 0; mt < 2; ++mt)
    #pragma unroll
    for (int nf = 0; nf < 2; ++nf)
      #pragma unroll
      for (int r = 0; r < 16; ++r) {
        int co = mt * 32 + (r & 3) + 8 * (r >> 2) + 4 * hi;
        o0[ob + (size_t)co * 16384 + nf * 32 + nlo] = acc0[mt][nf][r] + bias[co];
      }
  if (nsets == 2) {
    #pragma unroll
    for (int mt = 0; mt < 2; ++mt)
      #pragma unroll
      for (int nf = 0; nf < 2; ++nf)
        #pragma unroll
        for (int r = 0; r < 16; ++r) {
          int co = mt * 32 + (r & 3) + 8 * (r >> 2) + 4 * hi;
          out1[ob + (size_t)co * 16384 + nf * 32 + nlo] = acc1[mt][nf][r] + bias[co];
        }
  }
}

// ---------- launch ----------
extern "C" void kernel_launch(void* const* d_in, const int* in_sizes, int n_in,
                              void* d_out, int out_size, void* d_ws, size_t ws_size,
                              hipStream_t stream) {
  const float* x    = (const float*)d_in[0];
  const float* xh   = (const float*)d_in[1];
  const float* cw   = (const float*)d_in[2];
  const float* hv   = (const float*)d_in[3];
  const float* bias = (const float*)d_in[4];

  float* out      = (float*)d_out;
  float* hash_out = out + 16777216;
  float* out_hash = out + 33554432;

  char* ws = (char*)d_ws;
  float* mm            = (float*)ws;
  char* zeropage       = ws + 128;                        // 16640 B
  unsigned short* w0F  = (unsigned short*)(ws + 32768);   // [9][8][64][8] bf16 frag layout
  unsigned short* w1F  = (unsigned short*)(ws + 106496);
  unsigned short* xbf  = (unsigned short*)(ws + 180224);  // [16][128][130][64] bf16
  unsigned short* xhbf = (unsigned short*)(ws + 180224 + 34078720);

  hipMemsetAsync(zeropage, 0, 16640, stream);
  minmax_kernel<<<1, 256, 0, stream>>>(cw, mm);
  hashprep_kernel<<<144, 256, 0, stream>>>(cw, hv, mm, w0F, w1F);
  xprep_kernel<<<4096, 256, 0, stream>>>(x, xh, xbf, xhbf);
  conv_kernel<<<2048, 256, 0, stream>>>(xbf, xhbf, zeropage, w0F, w1F, bias,
                                        out, hash_out, out_hash);
}